// Round 5
// baseline (394.428 us; speedup 1.0000x reference)
//
#include <hip/hip_runtime.h>
#include <cstddef>

// DIN attention, R5: batch-independent B-matrix.
// preact1[l,h] = qt[h] + sum_k ub[l,k]*A1[k,h] + sum_k (ub[l,k]*q[k])*A2[k,h]
//   A1 = W1b - W1c, A2 = W1d  (rows 128.. / 256.. / 384.. of w1) -> FIXED across batch
//   qt[h] = b1[h] + sum_k q[k]*(W1a+W1c)[k,h]
// GEMM1: A=[ub, ub*q] (200x256 bf16) @ B=[A1;A2] (256x80), 13x5 tiles, 8 ksteps
// (paired per kc: plain + mul). layer2: 13x3 tiles, K=80 pad 96, pads zeroed.
// LDS frags packed as contiguous 16B slots: lane reads base+lane (conflict-free).

#define L_   200
#define D2_  128

typedef __attribute__((ext_vector_type(8))) short bf16x8;
typedef __attribute__((ext_vector_type(4))) float f32x4;
typedef __attribute__((ext_vector_type(4))) unsigned int u32x4;

__device__ __forceinline__ float sigmoidf_(float x) { return 1.0f / (1.0f + __expf(-x)); }

__device__ __forceinline__ unsigned int f2bf_(float x) {
  unsigned int u = __float_as_uint(x);
  return (u + 0x7fffu + ((u >> 16) & 1u)) >> 16;   // RNE, low 16 bits valid
}
__device__ __forceinline__ unsigned int pk2_(float a, float b) {
  return f2bf_(a) | (f2bf_(b) << 16);
}
__device__ __forceinline__ float f4get(const float4& v, int c) {
  return c == 0 ? v.x : c == 1 ? v.y : c == 2 ? v.z : v.w;
}

extern "C" __global__ void __launch_bounds__(256, 2)
din_attn_kernel(const float* __restrict__ queries,
                const float* __restrict__ ub,
                const int*   __restrict__ masks,
                const float* __restrict__ w1,
                const float* __restrict__ b1,
                const float* __restrict__ w2,
                const float* __restrict__ b2,
                const float* __restrict__ w3,
                float* __restrict__ out)
{
  // region0: Bfix frags (2560 slots, 40960B) -> hv frags (2496 slots) -> wsum
  // region1: A kc-pair chunk (832 plain + 832 mul slots, 26624B) -> w2f (576 slots)
  __shared__ __align__(16) char region0[40960];
  __shared__ __align__(16) char region1[26624];
  __shared__ __align__(16) float qtp[640];
  __shared__ __align__(16) float q_s[128];
  __shared__ __align__(16) float qt_s[80];
  __shared__ __align__(16) float b2_s[48];
  __shared__ __align__(16) float w3_s[48];
  __shared__ __align__(16) float scores_s[208];
  __shared__ float red_s[8];

  const int b    = blockIdx.x;
  const int t    = threadIdx.x;
  const int wave = t >> 6;
  const int lane = t & 63;

  const float* ubbase = ub + (size_t)b * L_ * D2_;
  const float4* ub4base = (const float4*)ubbase;

  // ---- stage q, b2, w3 ----
  if (t < 128) q_s[t] = queries[(size_t)b * D2_ + t];
  if (t < 48) {
    b2_s[t] = (t < 40) ? b2[t] : 0.0f;
    w3_s[t] = (t < 40) ? w3[t] : 0.0f;
  }
  __syncthreads();

  // ---- build Bfix frags: slot s=((kc*5+nt)*4+kg)*16+n = B[k0..k0+7][h=nt*16+n]
  //      task u=(kc,kg,h4): 16 (or 8) float4 loads, 4 contiguous slot writes ----
  {
    u32x4* Bdst = (u32x4*)region0;
    #pragma unroll
    for (int i = 0; i < 3; ++i) {
      int u = i * 256 + t;
      if (u < 640) {
        int h4 = u % 20;
        int r  = u / 20;
        int kg = r & 3, kc = r >> 2;
        int k0 = kc * 32 + kg * 8;
        int hb = h4 * 4;
        float4 v[8];
        if (kc < 4) {
          #pragma unroll
          for (int j = 0; j < 8; ++j) {
            float4 p = *(const float4*)(w1 + (128 + k0 + j) * 80 + hb);
            float4 c = *(const float4*)(w1 + (256 + k0 + j) * 80 + hb);
            v[j] = make_float4(p.x - c.x, p.y - c.y, p.z - c.z, p.w - c.w);
          }
        } else {
          int k0p = k0 - 128;
          #pragma unroll
          for (int j = 0; j < 8; ++j)
            v[j] = *(const float4*)(w1 + (384 + k0p + j) * 80 + hb);
        }
        int nt = hb >> 4, n = hb & 15;
        int sbase = ((kc * 5 + nt) * 4 + kg) * 16 + n;
        #pragma unroll
        for (int hh = 0; hh < 4; ++hh) {
          u32x4 w = { pk2_(f4get(v[0], hh), f4get(v[1], hh)),
                      pk2_(f4get(v[2], hh), f4get(v[3], hh)),
                      pk2_(f4get(v[4], hh), f4get(v[5], hh)),
                      pk2_(f4get(v[6], hh), f4get(v[7], hh)) };
          Bdst[sbase + hh] = w;
        }
      }
    }
  }

  // ---- qt partials: task (h4, kseg): float4 over h, 16 k's ----
  if (t < 160) {
    int h4 = t % 20, kseg = t / 20;
    int k0 = kseg * 16, hb = h4 * 4;
    float4 accq = make_float4(0.f, 0.f, 0.f, 0.f);
    #pragma unroll
    for (int k = 0; k < 16; ++k) {
      float qk = q_s[k0 + k];
      float4 a = *(const float4*)(w1 + (k0 + k) * 80 + hb);
      float4 c = *(const float4*)(w1 + (256 + k0 + k) * 80 + hb);
      accq.x += qk * (a.x + c.x); accq.y += qk * (a.y + c.y);
      accq.z += qk * (a.z + c.z); accq.w += qk * (a.w + c.w);
    }
    *(float4*)(qtp + (kseg * 20 + h4) * 4) = accq;
  }
  __syncthreads();
  if (t < 80) {
    float accq = b1[t];
    int h4 = t >> 2, hh = t & 3;
    #pragma unroll
    for (int ks = 0; ks < 8; ++ks) accq += qtp[(ks * 20 + h4) * 4 + hh];
    qt_s[t] = accq;
  }

  // ---- GEMM1: 65 tiles over 4 waves, 4 kc iters x 2 ksteps (plain/mul) ----
  f32x4 acc[17];
  #pragma unroll
  for (int i = 0; i < 17; ++i) acc[i] = (f32x4){0.f, 0.f, 0.f, 0.f};

  const bf16x8* Bf = (const bf16x8*)region0;
  const bf16x8* Ap = (const bf16x8*)region1;
  const bf16x8* Am = (const bf16x8*)(region1 + 13312);

  for (int kc = 0; kc < 4; ++kc) {
    u32x4* dp = (u32x4*)region1;
    u32x4* dm = (u32x4*)(region1 + 13312);
    #pragma unroll
    for (int i = 0; i < 4; ++i) {
      int s = i * 256 + t;
      if (s < 832) {
        int m = s & 15, kg = (s >> 4) & 3, mt = s >> 6;
        int l = mt * 16 + m;
        u32x4 vp = { 0u, 0u, 0u, 0u }, vm = { 0u, 0u, 0u, 0u };
        if (l < L_) {
          const float4* src = (const float4*)(ubbase + (size_t)l * D2_ + kc * 32 + kg * 8);
          float4 u0 = src[0], u1 = src[1];
          const float4* qq = (const float4*)(q_s + kc * 32 + kg * 8);
          float4 q0 = qq[0], q1 = qq[1];
          vp = (u32x4){ pk2_(u0.x, u0.y), pk2_(u0.z, u0.w),
                        pk2_(u1.x, u1.y), pk2_(u1.z, u1.w) };
          vm = (u32x4){ pk2_(u0.x * q0.x, u0.y * q0.y), pk2_(u0.z * q0.z, u0.w * q0.w),
                        pk2_(u1.x * q1.x, u1.y * q1.y), pk2_(u1.z * q1.z, u1.w * q1.w) };
        }
        dp[s] = vp; dm[s] = vm;
      }
    }
    __syncthreads();

    #pragma unroll
    for (int i = 0; i < 17; ++i) {
      int tt = i * 4 + wave;
      if (tt < 65) {
        int mt = tt / 5, nt = tt - mt * 5;
        bf16x8 avp = Ap[mt * 64 + lane];
        bf16x8 avm = Am[mt * 64 + lane];
        bf16x8 bvp = Bf[(kc * 5 + nt) * 64 + lane];
        bf16x8 bvm = Bf[((kc + 4) * 5 + nt) * 64 + lane];
        acc[i] = __builtin_amdgcn_mfma_f32_16x16x32_bf16(avp, bvp, acc[i], 0, 0, 0);
        acc[i] = __builtin_amdgcn_mfma_f32_16x16x32_bf16(avm, bvm, acc[i], 0, 0, 0);
      }
    }
    __syncthreads();
  }

  // ---- epilogue1: hv = sigmoid(preact1) -> A-frag layout in region0; zero K-pads ----
  {
    u32x4* pz = (u32x4*)region0;
    #pragma unroll
    for (int s = 0; s < 2; ++s) {
      int idx = s * 256 + t;
      if (idx < 416) {
        int mt = idx >> 5, off = idx & 31;
        pz[(mt * 12 + 10) * 16 + off] = (u32x4){ 0u, 0u, 0u, 0u };
      }
    }
    unsigned short* hv = (unsigned short*)region0;
    const int n = lane & 15, rg = lane >> 4;
    #pragma unroll
    for (int i = 0; i < 17; ++i) {
      int tt = i * 4 + wave;
      if (tt < 65) {
        int mt = tt / 5, nt = tt - mt * 5;
        int h = nt * 16 + n;
        int kg = h >> 3, hb = h & 7;
        float qtv = qt_s[h];
        #pragma unroll
        for (int r = 0; r < 4; ++r) {
          float x = acc[i][r] + qtv;
          hv[((mt * 12 + kg) * 16 + rg * 4 + r) * 8 + hb] =
              (unsigned short)f2bf_(sigmoidf_(x));
        }
      }
    }
  }

  // ---- build w2 B-frags in region1 (A-chunk dead after last GEMM sync) ----
  {
    u32x4* dst = (u32x4*)region1;
    #pragma unroll
    for (int i = 0; i < 3; ++i) {
      int s = i * 256 + t;
      if (s < 576) {
        int n = s & 15, g = s >> 4;
        int nt2 = g / 12, kg = g - nt2 * 12;
        int j = nt2 * 16 + n;
        u32x4 v = { 0u, 0u, 0u, 0u };
        if (j < 40 && kg < 10) {
          int k0 = kg * 8;
          float e0 = w2[(k0 + 0) * 40 + j], e1 = w2[(k0 + 1) * 40 + j];
          float e2 = w2[(k0 + 2) * 40 + j], e3 = w2[(k0 + 3) * 40 + j];
          float e4 = w2[(k0 + 4) * 40 + j], e5 = w2[(k0 + 5) * 40 + j];
          float e6 = w2[(k0 + 6) * 40 + j], e7 = w2[(k0 + 7) * 40 + j];
          v = (u32x4){ pk2_(e0, e1), pk2_(e2, e3), pk2_(e4, e5), pk2_(e6, e7) };
        }
        dst[s] = v;
      }
    }
  }
  __syncthreads();

  // ---- layer2: C2[l,j], 13x3 tiles, K=96 (A pads zeroed, B pads zeroed) ----
  f32x4 acc2[4][3];
  #pragma unroll
  for (int i = 0; i < 4; ++i)
    #pragma unroll
    for (int n2 = 0; n2 < 3; ++n2) acc2[i][n2] = (f32x4){0.f, 0.f, 0.f, 0.f};

  {
    const bf16x8* hvf = (const bf16x8*)region0;
    const bf16x8* w2ff = (const bf16x8*)region1;
    #pragma unroll
    for (int i = 0; i < 4; ++i) {
      int mt = wave + i * 4;
      if (mt < 13) {
        #pragma unroll
        for (int ks = 0; ks < 3; ++ks) {
          bf16x8 av = hvf[mt * 192 + ks * 64 + lane];
          #pragma unroll
          for (int n2 = 0; n2 < 3; ++n2) {
            bf16x8 bv = w2ff[n2 * 192 + ks * 64 + lane];
            acc2[i][n2] = __builtin_amdgcn_mfma_f32_16x16x32_bf16(av, bv, acc2[i][n2], 0, 0, 0);
          }
        }
      }
    }
  }

  // ---- epilogue2: score_l = sum_j sigmoid(p2+b2[j])*w3[j]; reduce 16 cols ----
  {
    const int n = lane & 15, rg = lane >> 4;
    #pragma unroll
    for (int i = 0; i < 4; ++i) {
      int mt = wave + i * 4;
      if (mt < 13) {
        #pragma unroll
        for (int r = 0; r < 4; ++r) {
          float s = 0.0f;
          #pragma unroll
          for (int n2 = 0; n2 < 3; ++n2) {
            int j = n2 * 16 + n;
            s += sigmoidf_(acc2[i][n2][r] + b2_s[j]) * w3_s[j];
          }
          s += __shfl_xor(s, 1, 64);
          s += __shfl_xor(s, 2, 64);
          s += __shfl_xor(s, 4, 64);
          s += __shfl_xor(s, 8, 64);
          int l = mt * 16 + rg * 4 + r;
          if (n == 0 && l < L_) scores_s[l] = s;
        }
      }
    }
  }
  __syncthreads();

  // ---- masked softmax over L (b3 omitted: softmax shift-invariant) ----
  float sval = -INFINITY;
  if (t < L_) {
    int mv = masks[(size_t)b * L_ + t];
    sval = mv ? scores_s[t] : -4294967295.0f;  // NEG_LARGE
  }
  float m = sval;
  #pragma unroll
  for (int o = 32; o > 0; o >>= 1) m = fmaxf(m, __shfl_xor(m, o, 64));
  if (lane == 0) red_s[wave] = m;
  __syncthreads();
  m = fmaxf(fmaxf(red_s[0], red_s[1]), fmaxf(red_s[2], red_s[3]));
  float e = (t < L_) ? __expf(sval - m) : 0.0f;
  float ssum = e;
  #pragma unroll
  for (int o = 32; o > 0; o >>= 1) ssum += __shfl_xor(ssum, o, 64);
  if (lane == 0) red_s[4 + wave] = ssum;
  __syncthreads();
  ssum = red_s[4] + red_s[5] + red_s[6] + red_s[7];
  float attn = e / ssum;
  __syncthreads();
  if (t < L_) scores_s[t] = attn;
  __syncthreads();

  // ---- weighted sum: out[d] = sum_l attn[l]*ub[l,d] (fp32, float4, 8-way l split) ----
  {
    float* wsum = (float*)region0;   // hv fully consumed by layer2 (sync'd above)
    int d4 = t & 31;
    int lg = t >> 5;
    float4 o = make_float4(0.f, 0.f, 0.f, 0.f);
    #pragma unroll 5
    for (int l = lg; l < L_; l += 8) {
      float w = scores_s[l];
      float4 v = ub4base[l * 32 + d4];
      o.x += w * v.x; o.y += w * v.y; o.z += w * v.z; o.w += w * v.w;
    }
    *(float4*)(wsum + lg * 136 + d4 * 4) = o;
    __syncthreads();
    if (t < 128) {
      float s = 0.0f;
      #pragma unroll
      for (int g = 0; g < 8; ++g) s += wsum[g * 136 + t];
      out[(size_t)b * 128 + t] = s;
    }
  }
}

extern "C" void kernel_launch(void* const* d_in, const int* in_sizes, int n_in,
                              void* d_out, int out_size, void* d_ws, size_t ws_size,
                              hipStream_t stream) {
  const float* queries = (const float*)d_in[0];
  const float* ub      = (const float*)d_in[1];
  const int*   masks   = (const int*)d_in[2];
  const float* w1      = (const float*)d_in[3];
  const float* b1      = (const float*)d_in[4];
  const float* w2      = (const float*)d_in[5];
  const float* b2      = (const float*)d_in[6];
  const float* w3      = (const float*)d_in[7];
  float* out = (float*)d_out;

  const int B = in_sizes[0] / D2_;   // 2048
  din_attn_kernel<<<B, 256, 0, stream>>>(queries, ub, masks, w1, b1, w2, b2, w3, out);
}